// Round 13
// baseline (299.832 us; speedup 1.0000x reference)
//
#include <hip/hip_runtime.h>
#include <hip/hip_bf16.h>

// Swin shifted-window attention, MI355X gfx950 — split pipeline v8.
// B=8, H=W=128, D=256, NHEAD=8, DK=32, WS=8, NH=NW=16, WSQ=64, SHIFT=4.
// qkv_k : segmented; seg0 stages x -> Q proj; seg1 stages z -> fused K+V proj.
//         Epilogue is WAVE-LOCAL (wave w owns head w): acc -> own LDS scratch
//         (pitch 40/72, 16B-aligned) -> ds_read_b128 -> 4x16B coalesced global
//         stores. Only 2 barriers/block (R12 had 6 + cooperative streaming).
// attnO_k: unchanged (near roofline): 2 heads/wave, P pitch 72, in-block O-GEMM.

typedef __bf16  bf16x8 __attribute__((ext_vector_type(8)));
typedef short   short8 __attribute__((ext_vector_type(8)));
typedef short   short4v __attribute__((ext_vector_type(4)));
typedef float   f32x4  __attribute__((ext_vector_type(4)));

#define SCALE_F 0.17677669529663687f

__device__ __forceinline__ short f2bs(float f){
    __hip_bfloat16 h = __float2bfloat16(f);
    return __builtin_bit_cast(short, h);
}
__device__ __forceinline__ short8 cvt8(float4 a, float4 b){
    short8 t;
    t[0]=f2bs(a.x); t[1]=f2bs(a.y); t[2]=f2bs(a.z); t[3]=f2bs(a.w);
    t[4]=f2bs(b.x); t[5]=f2bs(b.y); t[6]=f2bs(b.z); t[7]=f2bs(b.w);
    return t;
}
__device__ __forceinline__ int strip3(int r, int c){
    if (c == 0) return 0;
    if (c == 1) return (r < 4) ? 0 : 1;
    return (r < 4) ? 2 : 0;
}

// ---------------- prep: weight transpose->bf16 + ADD table ------------------
__global__ __launch_bounds__(256) void prep_k(const float* __restrict__ Wq,
                                              const float* __restrict__ Wkv,
                                              const float* __restrict__ Wo,
                                              const float* __restrict__ rel,
                                              short* __restrict__ Wqt,
                                              short* __restrict__ Wkvt,
                                              short* __restrict__ Wot,
                                              float* __restrict__ ADD){
    int i = blockIdx.x * 256 + threadIdx.x;
    if (i < 65536){
        int n = i >> 8, k = i & 255;
        Wqt[i] = f2bs(Wq[k * 256 + n]);
    } else if (i < 196608){
        int j = i - 65536;
        int n = j >> 8, k = j & 255;
        Wkvt[j] = f2bs(Wkv[k * 512 + n]);
    } else if (i < 262144){
        int j = i - 196608;
        int n = j >> 8, k = j & 255;
        Wot[j] = f2bs(Wo[k * 256 + n]);
    } else {
        int j = i - 262144;
        int k = j & 63, q = (j >> 6) & 63, head = (j >> 12) & 7, cls = j >> 15;
        int wiC = cls / 3, wjC = cls - wiC * 3;
        int qr = q >> 3, qc = q & 7, kr = k >> 3, kc = k & 7;
        int lq = strip3(qr, wiC) * 3 + strip3(qc, wjC);
        int lk = strip3(kr, wiC) * 3 + strip3(kc, wjC);
        float pe = rel[((qr - kr + 7) * 15 + (qc - kc + 7)) * 8 + head];
        ADD[j] = (lq != lk) ? -1e9f : pe;
    }
}

// ---------------- k1: QKV projection, wave-local coalesced epilogues --------
// LDS: staging [64][264]=16896 shorts; overlay after proj-sync:
//      8 per-wave scratch regions of 2560 shorts (Q/K [64][40], V [32][72]).
// Total 20480 shorts = 40960 B -> exactly 4 blocks/CU.
__global__ __launch_bounds__(512, 4) void qkv_k(
    const float* __restrict__ x, const float* __restrict__ z,
    const short* __restrict__ Wqt, const short* __restrict__ Wkvt,
    const float* __restrict__ bq, const float* __restrict__ bkv,
    short* __restrict__ Qw, short* __restrict__ Kw, short* __restrict__ Vw){
    __shared__ __align__(16) short lds[20480];
    const int tid = threadIdx.x, w = tid >> 6, lane = tid & 63;
    const int l15 = lane & 15, g = lane >> 4;
    const int bx = blockIdx.x;
    const int seg = bx >> 11, win = bx & 2047;
    const int wj = win & 15, wi = (win >> 4) & 15, b = win >> 8;
    const float* __restrict__ src = seg ? z : x;
    const f32x4 zero = {0.f,0.f,0.f,0.f};

    // stage window -> LDS bf16 [64][264]
#pragma unroll
    for (int i=0;i<4;++i){
        const int u = tid + i*512;
        const int p = u >> 5, c8 = u & 31;
        const int pr = ((wi << 3) + (p >> 3) + 4) & 127;
        const int pc = ((wj << 3) + (p & 7) + 4) & 127;
        const size_t gidx = ((((((size_t)b << 7) | pr) << 7) | pc) << 8) + c8*8;
        const float4* sp = reinterpret_cast<const float4*>(src + gidx);
        float4 a0 = sp[0], a1 = sp[1];
        *reinterpret_cast<short8*>(lds + p*264 + c8*8) = cvt8(a0, a1);
    }
    __syncthreads();                                   // (1)

    const int c0 = w * 32;
    const size_t base = ((((size_t)b*8 + w)*16 + wi)*16 + wj) * 2048;
    short* scr = lds + w * 2560;

    if (seg == 0){
        // ---- Q projection ----
        f32x4 acc[4][2];
#pragma unroll
        for (int mi=0;mi<4;++mi){ acc[mi][0]=zero; acc[mi][1]=zero; }
#pragma unroll
        for (int kt=0;kt<8;++kt){
            bf16x8 af[4], wf[2];
#pragma unroll
            for (int nj=0;nj<2;++nj)
                wf[nj] = *reinterpret_cast<const bf16x8*>(Wqt + (size_t)(c0 + nj*16 + l15)*256 + kt*32 + g*8);
#pragma unroll
            for (int mi=0;mi<4;++mi)
                af[mi] = *reinterpret_cast<const bf16x8*>(lds + (mi*16 + l15)*264 + kt*32 + g*8);
#pragma unroll
            for (int mi=0;mi<4;++mi)
#pragma unroll
                for (int nj=0;nj<2;++nj)
                    acc[mi][nj] = __builtin_amdgcn_mfma_f32_16x16x32_bf16(af[mi], wf[nj], acc[mi][nj], 0,0,0);
        }
        __syncthreads();                               // (2) staging dead
        // wave-local transpose: acc -> scr[64][40]
#pragma unroll
        for (int nj=0;nj<2;++nj){
            float bv = bq[c0 + nj*16 + l15];
#pragma unroll
            for (int mi=0;mi<4;++mi)
#pragma unroll
                for (int r=0;r<4;++r)
                    scr[(mi*16 + g*4 + r)*40 + nj*16 + l15] = f2bs(acc[mi][nj][r] + bv);
        }
        // wave-local readback + coalesced store (lane = pixel, 64B contiguous)
        {
            const short* rp = scr + lane*40;
            short* dst = Qw + base + lane*32;
#pragma unroll
            for (int c2=0;c2<4;++c2)
                *reinterpret_cast<short8*>(dst + c2*8) = *reinterpret_cast<const short8*>(rp + c2*8);
        }
    } else {
        // ---- fused K+V projection (shared A fragments) ----
        f32x4 accK[4][2], accV[4][2];
#pragma unroll
        for (int mi=0;mi<4;++mi){
            accK[mi][0]=zero; accK[mi][1]=zero;
            accV[mi][0]=zero; accV[mi][1]=zero;
        }
#pragma unroll
        for (int kt=0;kt<8;++kt){
            bf16x8 af[4], wfK[2], wfV[2];
#pragma unroll
            for (int nj=0;nj<2;++nj){
                wfK[nj] = *reinterpret_cast<const bf16x8*>(Wkvt + (size_t)(c0 + nj*16 + l15)*256 + kt*32 + g*8);
                wfV[nj] = *reinterpret_cast<const bf16x8*>(Wkvt + (size_t)(256 + c0 + nj*16 + l15)*256 + kt*32 + g*8);
            }
#pragma unroll
            for (int mi=0;mi<4;++mi)
                af[mi] = *reinterpret_cast<const bf16x8*>(lds + (mi*16 + l15)*264 + kt*32 + g*8);
#pragma unroll
            for (int mi=0;mi<4;++mi)
#pragma unroll
                for (int nj=0;nj<2;++nj){
                    accK[mi][nj] = __builtin_amdgcn_mfma_f32_16x16x32_bf16(af[mi], wfK[nj], accK[mi][nj], 0,0,0);
                    accV[mi][nj] = __builtin_amdgcn_mfma_f32_16x16x32_bf16(af[mi], wfV[nj], accV[mi][nj], 0,0,0);
                }
        }
        __syncthreads();                               // (2) staging dead
        // K: wave-local transpose scr[64][40] -> coalesced store
#pragma unroll
        for (int nj=0;nj<2;++nj){
            float bv = bkv[c0 + nj*16 + l15];
#pragma unroll
            for (int mi=0;mi<4;++mi)
#pragma unroll
                for (int r=0;r<4;++r)
                    scr[(mi*16 + g*4 + r)*40 + nj*16 + l15] = f2bs(accK[mi][nj][r] + bv);
        }
        {
            const short* rp = scr + lane*40;
            short* dst = Kw + base + lane*32;
#pragma unroll
            for (int c2=0;c2<4;++c2)
                *reinterpret_cast<short8*>(dst + c2*8) = *reinterpret_cast<const short8*>(rp + c2*8);
        }
        // V: wave-local transpose scr[32][72] ([dk][pix]) -> coalesced store
#pragma unroll
        for (int nj=0;nj<2;++nj){
            float bv = bkv[256 + c0 + nj*16 + l15];
            const int dk = nj*16 + l15;
#pragma unroll
            for (int mi=0;mi<4;++mi){
                short4v t;
#pragma unroll
                for (int r=0;r<4;++r) t[r] = f2bs(accV[mi][nj][r] + bv);
                *reinterpret_cast<short4v*>(scr + dk*72 + mi*16 + g*4) = t;
            }
        }
        {
            // flat V offset lane*32 == (lane>>1)*64 + (lane&1)*32 in [dk][pix]
            const short* vp = scr + (lane >> 1)*72 + ((lane & 1) << 5);
            short* dst = Vw + base + lane*32;
#pragma unroll
            for (int c2=0;c2<4;++c2)
                *reinterpret_cast<short8*>(dst + c2*8) = *reinterpret_cast<const short8*>(vp + c2*8);
        }
    }
}

// ---------------- k2: attention + O-GEMM ------------------------------------
// LDS: 4x P[64][72] (18432) + att[64][264] (16896) = 35328 shorts = 70.6 KB
__global__ __launch_bounds__(256, 2) void attnO_k(
    const short* __restrict__ Qw, const short* __restrict__ Kw,
    const short* __restrict__ Vw, const short* __restrict__ Wot,
    const float* __restrict__ bo, const float* __restrict__ ADD,
    float* __restrict__ out){
    __shared__ __align__(16) short lds[35328];
    const int tid = threadIdx.x, w = tid >> 6, lane = tid & 63;
    const int l15 = lane & 15, g = lane >> 4;
    const int bx = blockIdx.x;
    const int wj = bx & 15, wi = (bx >> 4) & 15, b = bx >> 8;
    const int wiC = (wi > 13) ? wi - 13 : 0;
    const int wjC = (wj > 13) ? wj - 13 : 0;
    short* P   = lds + w * 4608;
    short* att = lds + 18432;
    const f32x4 zero = {0.f,0.f,0.f,0.f};

    for (int hh = 0; hh < 2; ++hh){
        const int h = w + hh * 4;
        const size_t base = ((((size_t)b*8 + h)*16 + wi)*16 + wj) * 2048;

        bf16x8 aq[4], bk[4];
#pragma unroll
        for (int mi=0;mi<4;++mi)
            aq[mi] = *reinterpret_cast<const bf16x8*>(Qw + base + (size_t)(mi*16 + l15)*32 + g*8);
#pragma unroll
        for (int ni=0;ni<4;++ni)
            bk[ni] = *reinterpret_cast<const bf16x8*>(Kw + base + (size_t)(ni*16 + l15)*32 + g*8);
        f32x4 s[4][4];
#pragma unroll
        for (int mi=0;mi<4;++mi)
#pragma unroll
            for (int ni=0;ni<4;++ni)
                s[mi][ni] = __builtin_amdgcn_mfma_f32_16x16x32_bf16(aq[mi], bk[ni], zero, 0,0,0);

        const float* addb = ADD + (size_t)(((wiC*3 + wjC)*8 + h) << 12);
        float rs[4][4];
#pragma unroll
        for (int mi=0;mi<4;++mi){
            const int qbase = mi*16 + g*4;
#pragma unroll
            for (int ni=0;ni<4;++ni){
                const int k = ni*16 + l15;
#pragma unroll
                for (int r=0;r<4;++r)
                    s[mi][ni][r] = fmaf(s[mi][ni][r], SCALE_F, addb[((qbase + r) << 6) + k]);
            }
#pragma unroll
            for (int r=0;r<4;++r){
                float mx = fmaxf(fmaxf(s[mi][0][r], s[mi][1][r]), fmaxf(s[mi][2][r], s[mi][3][r]));
                mx = fmaxf(mx, __shfl_xor(mx, 1));
                mx = fmaxf(mx, __shfl_xor(mx, 2));
                mx = fmaxf(mx, __shfl_xor(mx, 4));
                mx = fmaxf(mx, __shfl_xor(mx, 8));
                float sum = 0.f;
#pragma unroll
                for (int ni=0;ni<4;++ni){
                    float p = __expf(s[mi][ni][r] - mx);
                    s[mi][ni][r] = p;
                    sum += p;
                }
                sum += __shfl_xor(sum, 1);
                sum += __shfl_xor(sum, 2);
                sum += __shfl_xor(sum, 4);
                sum += __shfl_xor(sum, 8);
                rs[mi][r] = 1.f / sum;
                const int q = qbase + r;
#pragma unroll
                for (int ni=0;ni<4;++ni)
                    P[q*72 + ni*16 + l15] = f2bs(s[mi][ni][r]);
            }
        }

        f32x4 o[4][2];
#pragma unroll
        for (int mi=0;mi<4;++mi){ o[mi][0]=zero; o[mi][1]=zero; }
#pragma unroll
        for (int ks=0;ks<2;++ks){
            bf16x8 pa[4], vb[2];
#pragma unroll
            for (int mi=0;mi<4;++mi)
                pa[mi] = *reinterpret_cast<const bf16x8*>(P + (mi*16 + l15)*72 + ks*32 + g*8);
#pragma unroll
            for (int nj=0;nj<2;++nj)
                vb[nj] = *reinterpret_cast<const bf16x8*>(Vw + base + (size_t)(nj*16 + l15)*64 + ks*32 + g*8);
#pragma unroll
            for (int mi=0;mi<4;++mi)
#pragma unroll
                for (int nj=0;nj<2;++nj)
                    o[mi][nj] = __builtin_amdgcn_mfma_f32_16x16x32_bf16(pa[mi], vb[nj], o[mi][nj], 0,0,0);
        }

#pragma unroll
        for (int mi=0;mi<4;++mi)
#pragma unroll
            for (int nj=0;nj<2;++nj)
#pragma unroll
                for (int r=0;r<4;++r)
                    att[(mi*16 + g*4 + r)*264 + h*32 + nj*16 + l15] = f2bs(o[mi][nj][r] * rs[mi][r]);
    }
    __syncthreads();

    f32x4 acc[4][4];
#pragma unroll
    for (int mi=0;mi<4;++mi)
#pragma unroll
        for (int nj=0;nj<4;++nj) acc[mi][nj] = zero;
#pragma unroll
    for (int kt=0;kt<8;++kt){
        bf16x8 af[4], bfm[4];
#pragma unroll
        for (int mi=0;mi<4;++mi)
            af[mi] = *reinterpret_cast<const bf16x8*>(att + (mi*16 + l15)*264 + kt*32 + g*8);
#pragma unroll
        for (int nj=0;nj<4;++nj)
            bfm[nj] = *reinterpret_cast<const bf16x8*>(Wot + (size_t)(w*64 + nj*16 + l15)*256 + kt*32 + g*8);
#pragma unroll
        for (int mi=0;mi<4;++mi)
#pragma unroll
            for (int nj=0;nj<4;++nj)
                acc[mi][nj] = __builtin_amdgcn_mfma_f32_16x16x32_bf16(af[mi], bfm[nj], acc[mi][nj], 0,0,0);
    }
#pragma unroll
    for (int nj=0;nj<4;++nj){
        const int col = w*64 + nj*16 + l15;
        const float bv = bo[col];
#pragma unroll
        for (int mi=0;mi<4;++mi)
#pragma unroll
            for (int r=0;r<4;++r){
                const int p = mi*16 + g*4 + r;
                const int pr = ((wi << 3) + (p >> 3) + 4) & 127;
                const int pc = ((wj << 3) + (p & 7) + 4) & 127;
                const size_t gp = ((((size_t)b << 7) | pr) << 7) | pc;
                out[gp * 256 + col] = acc[mi][nj][r] + bv;
            }
    }
}

extern "C" void kernel_launch(void* const* d_in, const int* in_sizes, int n_in,
                              void* d_out, int out_size, void* d_ws, size_t ws_size,
                              hipStream_t stream) {
    const float* x    = (const float*)d_in[0];
    const float* z    = (const float*)d_in[1];
    const float* Wq   = (const float*)d_in[2];
    const float* bq   = (const float*)d_in[3];
    const float* Wkv  = (const float*)d_in[4];
    const float* bkv  = (const float*)d_in[5];
    const float* Wo   = (const float*)d_in[6];
    const float* bo   = (const float*)d_in[7];
    const float* rel  = (const float*)d_in[8];

    char* ws = (char*)d_ws;
    short* Wqt  = (short*)(ws);                     // 128 KiB
    short* Wkvt = (short*)(ws + 131072);            // 256 KiB
    short* Wot  = (short*)(ws + 393216);            // 128 KiB
    float* ADD  = (float*)(ws + 524288);            // 1.125 MiB
    short* Qw   = (short*)(ws + 2097152);           // 64 MiB
    short* Kw   = (short*)(ws + 69206016);          // 64 MiB
    short* Vw   = (short*)(ws + 136314880);         // 64 MiB

    prep_k <<<2176, 256, 0, stream>>>(Wq, Wkv, Wo, rel, Wqt, Wkvt, Wot, ADD);
    qkv_k  <<<4096, 512, 0, stream>>>(x, z, Wqt, Wkvt, bq, bkv, Qw, Kw, Vw);
    attnO_k<<<2048, 256, 0, stream>>>(Qw, Kw, Vw, Wot, bo, ADD, (float*)d_out);
}

// Round 14
// 263.424 us; speedup vs baseline: 1.1382x; 1.1382x over previous
//
#include <hip/hip_runtime.h>
#include <hip/hip_bf16.h>

// Swin shifted-window attention, MI355X gfx950 — split pipeline v9.
// B=8, H=W=128, D=256, NHEAD=8, DK=32, WS=8, NH=NW=16, WSQ=64, SHIFT=4.
// qkv_k : async f32 staging via global_load_lds (wave-uniform LDS row base,
//         XOR-swizzled per-lane GLOBAL source; LDS linear). Fragments cvt'd
//         f32->bf16 on read (VALU headroom). Epilogue = R12 cooperative
//         coalesced stream (WRITE amplification fix, proven).
// attnO_k: unchanged (near its roofline).

typedef __bf16  bf16x8 __attribute__((ext_vector_type(8)));
typedef short   short8 __attribute__((ext_vector_type(8)));
typedef short   short4v __attribute__((ext_vector_type(4)));
typedef float   f32x4  __attribute__((ext_vector_type(4)));

#define SCALE_F 0.17677669529663687f

__device__ __forceinline__ short f2bs(float f){
    __hip_bfloat16 h = __float2bfloat16(f);
    return __builtin_bit_cast(short, h);
}
__device__ __forceinline__ short8 cvt8(float4 a, float4 b){
    short8 t;
    t[0]=f2bs(a.x); t[1]=f2bs(a.y); t[2]=f2bs(a.z); t[3]=f2bs(a.w);
    t[4]=f2bs(b.x); t[5]=f2bs(b.y); t[6]=f2bs(b.z); t[7]=f2bs(b.w);
    return t;
}
__device__ __forceinline__ int strip3(int r, int c){
    if (c == 0) return 0;
    if (c == 1) return (r < 4) ? 0 : 1;
    return (r < 4) ? 2 : 0;
}
// fragment read from swizzled f32 LDS: row p, 16B-chunk index c (8 floats = c, c+1)
__device__ __forceinline__ bf16x8 fragf(const float* __restrict__ ldsf, int p, int c){
    const int s = p & 7;
    float4 a0 = *reinterpret_cast<const float4*>(ldsf + p*256 + ((c ^ s) << 2));
    float4 a1 = *reinterpret_cast<const float4*>(ldsf + p*256 + (((c + 1) ^ s) << 2));
    return __builtin_bit_cast(bf16x8, cvt8(a0, a1));
}

// ---------------- prep: weight transpose->bf16 + ADD table ------------------
__global__ __launch_bounds__(256) void prep_k(const float* __restrict__ Wq,
                                              const float* __restrict__ Wkv,
                                              const float* __restrict__ Wo,
                                              const float* __restrict__ rel,
                                              short* __restrict__ Wqt,
                                              short* __restrict__ Wkvt,
                                              short* __restrict__ Wot,
                                              float* __restrict__ ADD){
    int i = blockIdx.x * 256 + threadIdx.x;
    if (i < 65536){
        int n = i >> 8, k = i & 255;
        Wqt[i] = f2bs(Wq[k * 256 + n]);
    } else if (i < 196608){
        int j = i - 65536;
        int n = j >> 8, k = j & 255;
        Wkvt[j] = f2bs(Wkv[k * 512 + n]);
    } else if (i < 262144){
        int j = i - 196608;
        int n = j >> 8, k = j & 255;
        Wot[j] = f2bs(Wo[k * 256 + n]);
    } else {
        int j = i - 262144;
        int k = j & 63, q = (j >> 6) & 63, head = (j >> 12) & 7, cls = j >> 15;
        int wiC = cls / 3, wjC = cls - wiC * 3;
        int qr = q >> 3, qc = q & 7, kr = k >> 3, kc = k & 7;
        int lq = strip3(qr, wiC) * 3 + strip3(qc, wjC);
        int lk = strip3(kr, wiC) * 3 + strip3(kc, wjC);
        float pe = rel[((qr - kr + 7) * 15 + (qc - kc + 7)) * 8 + head];
        ADD[j] = (lq != lk) ? -1e9f : pe;
    }
}

// ---------------- k1: QKV projection, async-staged f32 ----------------------
// LDS: 16384 floats (64 KB): staging [64][256] f32 (XOR-swizzled chunks);
//      after proj-sync, overlaid (as shorts) by R12's epilogue regions.
__global__ __launch_bounds__(512, 4) void qkv_k(
    const float* __restrict__ x, const float* __restrict__ z,
    const short* __restrict__ Wqt, const short* __restrict__ Wkvt,
    const float* __restrict__ bq, const float* __restrict__ bkv,
    short* __restrict__ Qw, short* __restrict__ Kw, short* __restrict__ Vw){
    __shared__ __align__(16) float ldsf[16384];
    short* sl = (short*)ldsf;
    const int tid = threadIdx.x, w = tid >> 6, lane = tid & 63;
    const int l15 = lane & 15, g = lane >> 4;
    const int bx = blockIdx.x;
    const int seg = bx >> 11, win = bx & 2047;
    const int wj = win & 15, wi = (win >> 4) & 15, b = win >> 8;
    const float* __restrict__ src = seg ? z : x;
    const f32x4 zero = {0.f,0.f,0.f,0.f};

    // ---- async stage: 8 issues/wave, one pixel row (1KB) per issue ----
#pragma unroll
    for (int i=0;i<8;++i){
        const int p = i*8 + w;
        const int pr = ((wi << 3) + (p >> 3) + 4) & 127;
        const int pc = ((wj << 3) + (p & 7) + 4) & 127;
        const float* gsrc = src + ((((((size_t)b << 7) | pr) << 7) | pc) << 8);
        const int off = (lane * 16) ^ ((p & 7) << 4);   // swizzled global source
        __builtin_amdgcn_global_load_lds(
            (const __attribute__((address_space(1))) void*)((const char*)gsrc + off),
            (__attribute__((address_space(3))) void*)((char*)ldsf + p * 1024),
            16, 0, 0);
    }
    __syncthreads();                                   // drains vmcnt (1)

    const int c0 = w * 32;
    const size_t winoff = ((size_t)wi*16 + wj) * 2048;

    if (seg == 0){
        // ---- Q projection ----
        f32x4 acc[4][2];
#pragma unroll
        for (int mi=0;mi<4;++mi){ acc[mi][0]=zero; acc[mi][1]=zero; }
#pragma unroll
        for (int kt=0;kt<8;++kt){
            bf16x8 af[4], wf[2];
#pragma unroll
            for (int nj=0;nj<2;++nj)
                wf[nj] = *reinterpret_cast<const bf16x8*>(Wqt + (size_t)(c0 + nj*16 + l15)*256 + kt*32 + g*8);
#pragma unroll
            for (int mi=0;mi<4;++mi)
                af[mi] = fragf(ldsf, mi*16 + l15, kt*8 + g*2);
#pragma unroll
            for (int mi=0;mi<4;++mi)
#pragma unroll
                for (int nj=0;nj<2;++nj)
                    acc[mi][nj] = __builtin_amdgcn_mfma_f32_16x16x32_bf16(af[mi], wf[nj], acc[mi][nj], 0,0,0);
        }
        __syncthreads();                               // (2) staging dead
        // results -> LDS [head w][pix][36]
#pragma unroll
        for (int nj=0;nj<2;++nj){
            float bv = bq[c0 + nj*16 + l15];
#pragma unroll
            for (int mi=0;mi<4;++mi)
#pragma unroll
                for (int r=0;r<4;++r)
                    sl[w*2304 + (mi*16 + g*4 + r)*36 + nj*16 + l15] = f2bs(acc[mi][nj][r] + bv);
        }
        __syncthreads();
        // coalesced stream: 8 windows x 4KB contiguous
        const int off = tid*4, p = off >> 5, c = off & 31;
#pragma unroll
        for (int hw=0; hw<8; ++hw){
            const size_t dstb = ((size_t)b*8 + hw)*524288 + winoff;
            *reinterpret_cast<short4v*>(Qw + dstb + off) =
                *reinterpret_cast<const short4v*>(sl + hw*2304 + p*36 + c);
        }
    } else {
        // ---- fused K+V projection (shared A fragments) ----
        f32x4 accK[4][2], accV[4][2];
#pragma unroll
        for (int mi=0;mi<4;++mi){
            accK[mi][0]=zero; accK[mi][1]=zero;
            accV[mi][0]=zero; accV[mi][1]=zero;
        }
#pragma unroll
        for (int kt=0;kt<8;++kt){
            bf16x8 af[4], wfK[2], wfV[2];
#pragma unroll
            for (int nj=0;nj<2;++nj){
                wfK[nj] = *reinterpret_cast<const bf16x8*>(Wkvt + (size_t)(c0 + nj*16 + l15)*256 + kt*32 + g*8);
                wfV[nj] = *reinterpret_cast<const bf16x8*>(Wkvt + (size_t)(256 + c0 + nj*16 + l15)*256 + kt*32 + g*8);
            }
#pragma unroll
            for (int mi=0;mi<4;++mi)
                af[mi] = fragf(ldsf, mi*16 + l15, kt*8 + g*2);
#pragma unroll
            for (int mi=0;mi<4;++mi)
#pragma unroll
                for (int nj=0;nj<2;++nj){
                    accK[mi][nj] = __builtin_amdgcn_mfma_f32_16x16x32_bf16(af[mi], wfK[nj], accK[mi][nj], 0,0,0);
                    accV[mi][nj] = __builtin_amdgcn_mfma_f32_16x16x32_bf16(af[mi], wfV[nj], accV[mi][nj], 0,0,0);
                }
        }
        __syncthreads();                               // (2) staging dead
        // K results -> LDS [head][pix][36]
#pragma unroll
        for (int nj=0;nj<2;++nj){
            float bv = bkv[c0 + nj*16 + l15];
#pragma unroll
            for (int mi=0;mi<4;++mi)
#pragma unroll
                for (int r=0;r<4;++r)
                    sl[w*2304 + (mi*16 + g*4 + r)*36 + nj*16 + l15] = f2bs(accK[mi][nj][r] + bv);
        }
        __syncthreads();
        {
            const int off = tid*4, p = off >> 5, c = off & 31;
#pragma unroll
            for (int hw=0; hw<8; ++hw){
                const size_t dstb = ((size_t)b*8 + hw)*524288 + winoff;
                *reinterpret_cast<short4v*>(Kw + dstb + off) =
                    *reinterpret_cast<const short4v*>(sl + hw*2304 + p*36 + c);
            }
        }
        __syncthreads();   // K stream done -> V overlay
        // V results -> LDS [head][dk][68] (transposed)
#pragma unroll
        for (int nj=0;nj<2;++nj){
            float bv = bkv[256 + c0 + nj*16 + l15];
            const int dk = nj*16 + l15;
#pragma unroll
            for (int mi=0;mi<4;++mi){
                short4v t;
#pragma unroll
                for (int r=0;r<4;++r) t[r] = f2bs(accV[mi][nj][r] + bv);
                *reinterpret_cast<short4v*>(sl + w*2176 + dk*68 + mi*16 + g*4) = t;
            }
        }
        __syncthreads();
        {
            const int off = tid*4, dk = off >> 6, pix = off & 63;
#pragma unroll
            for (int hw=0; hw<8; ++hw){
                const size_t dstb = ((size_t)b*8 + hw)*524288 + winoff;
                *reinterpret_cast<short4v*>(Vw + dstb + off) =
                    *reinterpret_cast<const short4v*>(sl + hw*2176 + dk*68 + pix);
            }
        }
    }
}

// ---------------- k2: attention + O-GEMM ------------------------------------
// LDS: 4x P[64][72] (18432) + att[64][264] (16896) = 35328 shorts = 70.6 KB
__global__ __launch_bounds__(256, 2) void attnO_k(
    const short* __restrict__ Qw, const short* __restrict__ Kw,
    const short* __restrict__ Vw, const short* __restrict__ Wot,
    const float* __restrict__ bo, const float* __restrict__ ADD,
    float* __restrict__ out){
    __shared__ __align__(16) short lds[35328];
    const int tid = threadIdx.x, w = tid >> 6, lane = tid & 63;
    const int l15 = lane & 15, g = lane >> 4;
    const int bx = blockIdx.x;
    const int wj = bx & 15, wi = (bx >> 4) & 15, b = bx >> 8;
    const int wiC = (wi > 13) ? wi - 13 : 0;
    const int wjC = (wj > 13) ? wj - 13 : 0;
    short* P   = lds + w * 4608;
    short* att = lds + 18432;
    const f32x4 zero = {0.f,0.f,0.f,0.f};

    for (int hh = 0; hh < 2; ++hh){
        const int h = w + hh * 4;
        const size_t base = ((((size_t)b*8 + h)*16 + wi)*16 + wj) * 2048;

        bf16x8 aq[4], bk[4];
#pragma unroll
        for (int mi=0;mi<4;++mi)
            aq[mi] = *reinterpret_cast<const bf16x8*>(Qw + base + (size_t)(mi*16 + l15)*32 + g*8);
#pragma unroll
        for (int ni=0;ni<4;++ni)
            bk[ni] = *reinterpret_cast<const bf16x8*>(Kw + base + (size_t)(ni*16 + l15)*32 + g*8);
        f32x4 s[4][4];
#pragma unroll
        for (int mi=0;mi<4;++mi)
#pragma unroll
            for (int ni=0;ni<4;++ni)
                s[mi][ni] = __builtin_amdgcn_mfma_f32_16x16x32_bf16(aq[mi], bk[ni], zero, 0,0,0);

        const float* addb = ADD + (size_t)(((wiC*3 + wjC)*8 + h) << 12);
        float rs[4][4];
#pragma unroll
        for (int mi=0;mi<4;++mi){
            const int qbase = mi*16 + g*4;
#pragma unroll
            for (int ni=0;ni<4;++ni){
                const int k = ni*16 + l15;
#pragma unroll
                for (int r=0;r<4;++r)
                    s[mi][ni][r] = fmaf(s[mi][ni][r], SCALE_F, addb[((qbase + r) << 6) + k]);
            }
#pragma unroll
            for (int r=0;r<4;++r){
                float mx = fmaxf(fmaxf(s[mi][0][r], s[mi][1][r]), fmaxf(s[mi][2][r], s[mi][3][r]));
                mx = fmaxf(mx, __shfl_xor(mx, 1));
                mx = fmaxf(mx, __shfl_xor(mx, 2));
                mx = fmaxf(mx, __shfl_xor(mx, 4));
                mx = fmaxf(mx, __shfl_xor(mx, 8));
                float sum = 0.f;
#pragma unroll
                for (int ni=0;ni<4;++ni){
                    float p = __expf(s[mi][ni][r] - mx);
                    s[mi][ni][r] = p;
                    sum += p;
                }
                sum += __shfl_xor(sum, 1);
                sum += __shfl_xor(sum, 2);
                sum += __shfl_xor(sum, 4);
                sum += __shfl_xor(sum, 8);
                rs[mi][r] = 1.f / sum;
                const int q = qbase + r;
#pragma unroll
                for (int ni=0;ni<4;++ni)
                    P[q*72 + ni*16 + l15] = f2bs(s[mi][ni][r]);
            }
        }

        f32x4 o[4][2];
#pragma unroll
        for (int mi=0;mi<4;++mi){ o[mi][0]=zero; o[mi][1]=zero; }
#pragma unroll
        for (int ks=0;ks<2;++ks){
            bf16x8 pa[4], vb[2];
#pragma unroll
            for (int mi=0;mi<4;++mi)
                pa[mi] = *reinterpret_cast<const bf16x8*>(P + (mi*16 + l15)*72 + ks*32 + g*8);
#pragma unroll
            for (int nj=0;nj<2;++nj)
                vb[nj] = *reinterpret_cast<const bf16x8*>(Vw + base + (size_t)(nj*16 + l15)*64 + ks*32 + g*8);
#pragma unroll
            for (int mi=0;mi<4;++mi)
#pragma unroll
                for (int nj=0;nj<2;++nj)
                    o[mi][nj] = __builtin_amdgcn_mfma_f32_16x16x32_bf16(pa[mi], vb[nj], o[mi][nj], 0,0,0);
        }

#pragma unroll
        for (int mi=0;mi<4;++mi)
#pragma unroll
            for (int nj=0;nj<2;++nj)
#pragma unroll
                for (int r=0;r<4;++r)
                    att[(mi*16 + g*4 + r)*264 + h*32 + nj*16 + l15] = f2bs(o[mi][nj][r] * rs[mi][r]);
    }
    __syncthreads();

    f32x4 acc[4][4];
#pragma unroll
    for (int mi=0;mi<4;++mi)
#pragma unroll
        for (int nj=0;nj<4;++nj) acc[mi][nj] = zero;
#pragma unroll
    for (int kt=0;kt<8;++kt){
        bf16x8 af[4], bfm[4];
#pragma unroll
        for (int mi=0;mi<4;++mi)
            af[mi] = *reinterpret_cast<const bf16x8*>(att + (mi*16 + l15)*264 + kt*32 + g*8);
#pragma unroll
        for (int nj=0;nj<4;++nj)
            bfm[nj] = *reinterpret_cast<const bf16x8*>(Wot + (size_t)(w*64 + nj*16 + l15)*256 + kt*32 + g*8);
#pragma unroll
        for (int mi=0;mi<4;++mi)
#pragma unroll
            for (int nj=0;nj<4;++nj)
                acc[mi][nj] = __builtin_amdgcn_mfma_f32_16x16x32_bf16(af[mi], bfm[nj], acc[mi][nj], 0,0,0);
    }
#pragma unroll
    for (int nj=0;nj<4;++nj){
        const int col = w*64 + nj*16 + l15;
        const float bv = bo[col];
#pragma unroll
        for (int mi=0;mi<4;++mi)
#pragma unroll
            for (int r=0;r<4;++r){
                const int p = mi*16 + g*4 + r;
                const int pr = ((wi << 3) + (p >> 3) + 4) & 127;
                const int pc = ((wj << 3) + (p & 7) + 4) & 127;
                const size_t gp = ((((size_t)b << 7) | pr) << 7) | pc;
                out[gp * 256 + col] = acc[mi][nj][r] + bv;
            }
    }
}

extern "C" void kernel_launch(void* const* d_in, const int* in_sizes, int n_in,
                              void* d_out, int out_size, void* d_ws, size_t ws_size,
                              hipStream_t stream) {
    const float* x    = (const float*)d_in[0];
    const float* z    = (const float*)d_in[1];
    const float* Wq   = (const float*)d_in[2];
    const float* bq   = (const float*)d_in[3];
    const float* Wkv  = (const float*)d_in[4];
    const float* bkv  = (const float*)d_in[5];
    const float* Wo   = (const float*)d_in[6];
    const float* bo   = (const float*)d_in[7];
    const float* rel  = (const float*)d_in[8];

    char* ws = (char*)d_ws;
    short* Wqt  = (short*)(ws);                     // 128 KiB
    short* Wkvt = (short*)(ws + 131072);            // 256 KiB
    short* Wot  = (short*)(ws + 393216);            // 128 KiB
    float* ADD  = (float*)(ws + 524288);            // 1.125 MiB
    short* Qw   = (short*)(ws + 2097152);           // 64 MiB
    short* Kw   = (short*)(ws + 69206016);          // 64 MiB
    short* Vw   = (short*)(ws + 136314880);         // 64 MiB

    prep_k <<<2176, 256, 0, stream>>>(Wq, Wkv, Wo, rel, Wqt, Wkvt, Wot, ADD);
    qkv_k  <<<4096, 512, 0, stream>>>(x, z, Wqt, Wkvt, bq, bkv, Qw, Kw, Vw);
    attnO_k<<<2048, 256, 0, stream>>>(Qw, Kw, Vw, Wot, bo, ADD, (float*)d_out);
}